// Round 9
// baseline (648.289 us; speedup 1.0000x reference)
//
#include <hip/hip_runtime.h>
#include <math.h>

// Problem constants (from reference)
#define N_NODES 100000
#define N_EDGES 1600000
#define E2      (N_NODES + N_EDGES)   // edges incl. self-loops = 1,700,000
#define IN_C    128
#define HID     64
#define HEADS   4
#define HH      256                    // HEADS*HID
#define OUT_C   2
#define NEG_SLOPE 0.2f

#define SB   1024                      // elements per scan block
#define NSB  ((N_NODES + SB - 1) / SB) // 98
#define GFILL ((N_EDGES + 255) / 256)  // 6250 fill blocks
#define GGEMM1 (N_NODES / 32)          // 3125 gemm1 blocks

__device__ __forceinline__ float bf2f(unsigned short u) {
    return __uint_as_float(((unsigned)u) << 16);
}
__device__ __forceinline__ unsigned short f2bf(float f) {
    unsigned u = __float_as_uint(f);
    u += 0x7fffu + ((u >> 16) & 1u);   // RNE
    return (unsigned short)(u >> 16);
}

// ---------------- CSR build ----------------
// cnt[] counts REAL edges only; degree = cnt+1 (self-loop). Self-loop is
// pre-placed at slot 0 of each segment by k_scan3; real edges fill slots 1..
// via atomics. hist/fill are 1 item/thread: x4/x2 ILP variants regressed
// (round 8, +30us) — latency-bound on memory-side atomics, more waves win.

__global__ void k_hist(const int* __restrict__ dst, int* __restrict__ cnt) {
    int i = blockIdx.x * 256 + threadIdx.x;
    if (i >= N_EDGES) return;
    atomicAdd(&cnt[dst[i]], 1);
}

// scan1: per-block sums of (cnt+1) -> bsum[NSB]; extra 8 blocks do prews.
// wsd[k][o<4] = sum_c W2[k][o*64+c]*att_src[o*64+c]; o>=4 -> att_dst
__global__ __launch_bounds__(256) void k_scan1(const int* __restrict__ cnt,
        int* __restrict__ bsum, const float* __restrict__ W2,
        const float* __restrict__ att_src, const float* __restrict__ att_dst,
        float* __restrict__ wsd) {
    int b = blockIdx.x, t = threadIdx.x;
    if (b >= NSB) {                      // prews tail blocks
        if (t < 64) {
            int g = (b - NSB) * 64 + t;  // 0..511
            int k = g >> 3, o = g & 7;
            int h = o & 3;
            const float* att = (o < 4) ? att_src : att_dst;
            float acc = 0.f;
            const float* wrow = W2 + (size_t)k * HH + h * 64;
            const float* arow = att + h * 64;
            for (int c = 0; c < 64; ++c) acc = fmaf(wrow[c], arow[c], acc);
            wsd[k * 8 + o] = acc;
        }
        return;
    }
    int i = b * SB + t * 4;
    int s = 0;
    if (i + 3 < N_NODES) {
        int4 v = *(const int4*)(cnt + i);
        s = (v.x + v.y) + (v.z + v.w) + 4;       // +1 self-loop per node
    } else {
        for (int k = 0; k < 4; ++k) if (i + k < N_NODES) s += cnt[i + k] + 1;
    }
#pragma unroll
    for (int off = 1; off < 64; off <<= 1) s += __shfl_xor(s, off);
    __shared__ int wsum[4];
    int lane = t & 63, wv = t >> 6;
    if (lane == 0) wsum[wv] = s;
    __syncthreads();
    if (t == 0) bsum[b] = (wsum[0] + wsum[1]) + (wsum[2] + wsum[3]);
}

// scan3: block b computes prefix over bsum[0..b) itself, scans its chunk
// (deg = cnt+1), writes rowptr + dinv, zeroes cur, pre-places self-loops.
__global__ __launch_bounds__(256) void k_scan3(const int* __restrict__ cnt,
        const int* __restrict__ bsum, int* __restrict__ rowptr,
        float* __restrict__ dinv, int* __restrict__ cur, int* __restrict__ col) {
    int b = blockIdx.x, t = threadIdx.x;
    int lane = t & 63, wv = t >> 6;
    __shared__ int wred[4];
    {
        int v = (t < b) ? bsum[t] : 0;   // b <= 98 <= 256
#pragma unroll
        for (int off = 1; off < 64; off <<= 1) v += __shfl_xor(v, off);
        if (lane == 0) wred[wv] = v;
    }
    __syncthreads();
    int pre = (wred[0] + wred[1]) + (wred[2] + wred[3]);
    __syncthreads();

    int i = b * SB + t * 4;
    int c0 = 0, c1 = 0, c2 = 0, c3 = 0;
    if (i + 3 < N_NODES) {
        int4 v = *(const int4*)(cnt + i);
        c0 = v.x; c1 = v.y; c2 = v.z; c3 = v.w;
    } else if (i < N_NODES) {
        c0 = cnt[i];
        if (i + 1 < N_NODES) c1 = cnt[i + 1];
        if (i + 2 < N_NODES) c2 = cnt[i + 2];
    }
    int n0 = (i < N_NODES), n1 = (i + 1 < N_NODES),
        n2 = (i + 2 < N_NODES), n3 = (i + 3 < N_NODES);
    int d0 = c0 + n0, d1 = c1 + n1, d2 = c2 + n2, d3 = c3 + n3;  // degrees
    int s = (d0 + d1) + (d2 + d3);
    int inc = s;
#pragma unroll
    for (int off = 1; off < 64; off <<= 1) {
        int u = __shfl_up(inc, off);
        if (lane >= off) inc += u;
    }
    __shared__ int wtot[4];
    if (lane == 63) wtot[wv] = inc;
    __syncthreads();
    int base = pre + (inc - s);
    for (int w = 0; w < wv; ++w) base += wtot[w];
    if (n0) { rowptr[i]     = base;                dinv[i]     = rsqrtf((float)d0); col[base] = i; }
    if (n1) { rowptr[i + 1] = base + d0;           dinv[i + 1] = rsqrtf((float)d1); col[base + d0] = i + 1; }
    if (n2) { rowptr[i + 2] = base + d0 + d1;      dinv[i + 2] = rsqrtf((float)d2); col[base + d0 + d1] = i + 2; }
    if (n3) { rowptr[i + 3] = base + d0 + d1 + d2; dinv[i + 3] = rsqrtf((float)d3); col[base + d0 + d1 + d2] = i + 3; }
    // zero cur for the fill pass
    if (n3) {
        *(int4*)(cur + i) = make_int4(0, 0, 0, 0);
    } else {
        for (int k = 0; k < 4; ++k) if (i + k < N_NODES) cur[i + k] = 0;
    }
    if (b == 0 && t == 0) rowptr[N_NODES] = E2;
}

// ---------------- fused fill + GEMM1 ----------------------------------------
// Blocks [0,GFILL): CSR fill (latency-bound, VALUBusy ~0.4%).
// Blocks [GFILL,GFILL+GGEMM1): xw1b = bf16((x @ W1) * dinv[row]) (VALU-bound).
// Independent work co-resident on each CU: gemm1's FMAs execute inside
// fill's memory-side atomic latency bubbles.
__global__ __launch_bounds__(256) void k_fill_gemm1(
        const int* __restrict__ ei, const int* __restrict__ rowptr,
        int* __restrict__ cur, int* __restrict__ col,
        const float* __restrict__ x, const float* __restrict__ W1,
        const float* __restrict__ dinv, unsigned short* __restrict__ xw1b) {
    __shared__ float xs[32 * IN_C];  // 16 KB (used by gemm1 path only)
    int t = threadIdx.x;
    if (blockIdx.x < GFILL) {
        int i = blockIdx.x * 256 + t;
        if (i >= N_EDGES) return;
        int s = ei[i], d = ei[N_EDGES + i];
        int pos = rowptr[d] + 1 + atomicAdd(&cur[d], 1);   // slot 0 = self-loop
        col[pos] = s;
        return;
    }
    int r0 = (blockIdx.x - GFILL) * 32;
    const float4* xg = (const float4*)(x + (size_t)r0 * IN_C);
    float4* xs4 = (float4*)xs;
#pragma unroll
    for (int i = 0; i < 4; ++i) xs4[i * 256 + t] = xg[i * 256 + t];
    int lane = t & 63, wv = t >> 6;
    float w[IN_C];
#pragma unroll
    for (int k = 0; k < IN_C; ++k) w[k] = W1[k * HID + lane];
    __syncthreads();
    for (int j0 = 0; j0 < 8; j0 += 2) {
        int ja = wv * 8 + j0, jb = ja + 1;
        const float4* xa = (const float4*)(xs + ja * IN_C);
        const float4* xb = (const float4*)(xs + jb * IN_C);
        float aA = 0.f, aB = 0.f;
#pragma unroll
        for (int kk = 0; kk < 32; ++kk) {
            float4 va = xa[kk], vb = xb[kk];
            aA = fmaf(va.x, w[4 * kk + 0], aA);
            aA = fmaf(va.y, w[4 * kk + 1], aA);
            aA = fmaf(va.z, w[4 * kk + 2], aA);
            aA = fmaf(va.w, w[4 * kk + 3], aA);
            aB = fmaf(vb.x, w[4 * kk + 0], aB);
            aB = fmaf(vb.y, w[4 * kk + 1], aB);
            aB = fmaf(vb.z, w[4 * kk + 2], aB);
            aB = fmaf(vb.w, w[4 * kk + 3], aB);
        }
        int ra = r0 + ja, rb = r0 + jb;
        xw1b[(size_t)ra * HID + lane] = f2bf(aA * dinv[ra]);
        xw1b[(size_t)rb * HID + lane] = f2bf(aB * dinv[rb]);
    }
}

// ---------------- GCN1 aggregate: h1b = bf16(relu(dinv*sum + b1)) -----------
// wave per dst; 16 lanes per edge (ushort4 = 4 bf16 ch/lane), 4 edges/group.
__global__ __launch_bounds__(256) void k_agg1(const int* __restrict__ rowptr,
        const int* __restrict__ col, const unsigned short* __restrict__ xw1b,
        const float* __restrict__ dinv, const float* __restrict__ b1,
        unsigned short* __restrict__ h1b) {
    int t = threadIdx.x;
    int lane = t & 63;
    int d = blockIdx.x * 4 + (t >> 6);
    if (d >= N_NODES) return;
    int start = rowptr[d], end = rowptr[d + 1];
    int sub = lane >> 4;       // which of 4 edges in a group
    int cpos = lane & 15;      // channel quad (4 bf16)
    float4 acc = make_float4(0.f, 0.f, 0.f, 0.f);
    for (int base = start; base < end; base += 64) {
        int cnt = min(64, end - base);
        int sl = (base + lane < end) ? col[base + lane] : 0;
#pragma unroll 2
        for (int j = 0; j < cnt; j += 4) {
            int idx = j + sub;
            int sj = __shfl(sl, idx);
            if (idx < cnt) {
                ushort4 v = ((const ushort4*)(xw1b + (size_t)sj * HID))[cpos];
                acc.x += bf2f(v.x); acc.y += bf2f(v.y);
                acc.z += bf2f(v.z); acc.w += bf2f(v.w);
            }
        }
    }
    acc.x += __shfl_xor(acc.x, 16); acc.y += __shfl_xor(acc.y, 16);
    acc.z += __shfl_xor(acc.z, 16); acc.w += __shfl_xor(acc.w, 16);
    acc.x += __shfl_xor(acc.x, 32); acc.y += __shfl_xor(acc.y, 32);
    acc.z += __shfl_xor(acc.z, 32); acc.w += __shfl_xor(acc.w, 32);
    if (lane < 16) {
        float di = dinv[d];
        float4 b = ((const float4*)b1)[lane];
        float ox = fmaf(acc.x, di, b.x); ox = ox > 0.f ? ox : 0.f;
        float oy = fmaf(acc.y, di, b.y); oy = oy > 0.f ? oy : 0.f;
        float oz = fmaf(acc.z, di, b.z); oz = oz > 0.f ? oz : 0.f;
        float ow = fmaf(acc.w, di, b.w); ow = ow > 0.f ? ow : 0.f;
        ushort4 o = make_ushort4(f2bf(ox), f2bf(oy), f2bf(oz), f2bf(ow));
        ((ushort4*)(h1b + (size_t)d * HID))[lane] = o;
    }
}

// ---------------- GEMM2: xw2b = bf16(h1 @ W2) [n][c*4+h], a_s, a_d ----------
__global__ __launch_bounds__(256) void k_gemm2(const unsigned short* __restrict__ h1b,
        const float* __restrict__ W2, const float* __restrict__ wsd,
        unsigned short* __restrict__ xw2b, float* __restrict__ a_s,
        float* __restrict__ a_d) {
    __shared__ float hs[32 * HID];   // 8 KB (fp32, converted at stage-in)
    __shared__ float ws[512];        // 2 KB
    int t = threadIdx.x;
    int r0 = blockIdx.x * 32;        // grid = N/32, exact
    const ushort4* hg = (const ushort4*)(h1b + (size_t)r0 * HID);  // 512 total
#pragma unroll
    for (int i = 0; i < 2; ++i) {
        ushort4 v = hg[i * 256 + t];
        ((float4*)hs)[i * 256 + t] =
            make_float4(bf2f(v.x), bf2f(v.y), bf2f(v.z), bf2f(v.w));
    }
    ((float2*)ws)[t] = ((const float2*)wsd)[t];
    float w[HID];
#pragma unroll
    for (int k = 0; k < HID; ++k) w[k] = W2[k * HH + t];
    __syncthreads();
    int lane = t & 63, h = t >> 6;
    for (int j = 0; j < 32; j += 2) {
        const float4* ha = (const float4*)(hs + j * HID);
        const float4* hb = (const float4*)(hs + (j + 1) * HID);
        float aA = 0.f, aB = 0.f;
#pragma unroll
        for (int kk = 0; kk < 16; ++kk) {
            float4 va = ha[kk], vb = hb[kk];
            aA = fmaf(va.x, w[4 * kk + 0], aA);
            aA = fmaf(va.y, w[4 * kk + 1], aA);
            aA = fmaf(va.z, w[4 * kk + 2], aA);
            aA = fmaf(va.w, w[4 * kk + 3], aA);
            aB = fmaf(vb.x, w[4 * kk + 0], aB);
            aB = fmaf(vb.y, w[4 * kk + 1], aB);
            aB = fmaf(vb.z, w[4 * kk + 2], aB);
            aB = fmaf(vb.w, w[4 * kk + 3], aB);
        }
        xw2b[(size_t)(r0 + j) * HH + lane * 4 + h] = f2bf(aA);
        xw2b[(size_t)(r0 + j + 1) * HH + lane * 4 + h] = f2bf(aB);
    }
    {
        int j = t >> 3, o = t & 7;
        const float* hrow = hs + j * HID;
        float acc = 0.f;
#pragma unroll
        for (int k = 0; k < 64; ++k) {
            int ke = (k + j) & 63;
            acc = fmaf(hrow[ke], ws[ke * 8 + o], acc);
        }
        int r = r0 + j;
        if (o < 4) a_s[r * 4 + o] = acc;
        else       a_d[r * 4 + (o - 4)] = acc;
    }
}

// ---------------- GAT aggregate + ELU + fused GEMM3 -------------------------
// unroll 4: unroll 8 raised VGPR 32->48, occupancy 79->48%, dur +14% (round 5)
// TWO half-range dispatches: keeps sub-max kernels visible in the top-5
// profile window (the window only ever shows the global max dispatch).
__global__ __launch_bounds__(256) void k_agg2(const int* __restrict__ rowptr,
        const int* __restrict__ col, const unsigned short* __restrict__ xw2b,
        const float* __restrict__ a_s, const float* __restrict__ a_d,
        const float* __restrict__ b2, const float* __restrict__ W3,
        const float* __restrict__ dinv, float2* __restrict__ xw3, int dbase) {
    __shared__ int   ss[4][64];      // 1 KB
    __shared__ float sp[4][64][4];   // 4 KB
    int t = threadIdx.x;
    int lane = t & 63, wv = t >> 6;
    int d = dbase + blockIdx.x * 4 + wv;
    if (d >= N_NODES) return;
    const float4* as4 = (const float4*)a_s;
    float4 adv = ((const float4*)a_d)[d];
    int start = rowptr[d], end = rowptr[d + 1];

    float den0 = 0.f, den1 = 0.f, den2 = 0.f, den3 = 0.f;
    float acc0 = 0.f, acc1 = 0.f, acc2 = 0.f, acc3 = 0.f;
    const ushort4* xw24 = (const ushort4*)xw2b;      // row = 64 ushort4
    for (int base = start; base < end; base += 64) {
        int cnt = min(64, end - base);
        float p0 = 0.f, p1 = 0.f, p2 = 0.f, p3 = 0.f;
        int s = 0;
        if (lane < cnt) {
            s = col[base + lane];
            float4 av = as4[s];
            float v;
            v = av.x + adv.x; v = v > 0.f ? v : NEG_SLOPE * v; p0 = __expf(v);
            v = av.y + adv.y; v = v > 0.f ? v : NEG_SLOPE * v; p1 = __expf(v);
            v = av.z + adv.z; v = v > 0.f ? v : NEG_SLOPE * v; p2 = __expf(v);
            v = av.w + adv.w; v = v > 0.f ? v : NEG_SLOPE * v; p3 = __expf(v);
            den0 += p0; den1 += p1; den2 += p2; den3 += p3;
        }
        ss[wv][lane] = s;                                  // wave-private LDS
        ((float4*)sp[wv])[lane] = make_float4(p0, p1, p2, p3);
#pragma unroll 4
        for (int j = 0; j < cnt; ++j) {
            int sj = ss[wv][j];                            // broadcast read
            float4 pj = ((const float4*)sp[wv])[j];        // broadcast read
            ushort4 xv = xw24[(size_t)sj * 64 + lane];     // 8B/lane coalesced
            acc0 = fmaf(pj.x, bf2f(xv.x), acc0);
            acc1 = fmaf(pj.y, bf2f(xv.y), acc1);
            acc2 = fmaf(pj.z, bf2f(xv.z), acc2);
            acc3 = fmaf(pj.w, bf2f(xv.w), acc3);
        }
    }
#pragma unroll
    for (int mk = 1; mk < 64; mk <<= 1) {
        den0 += __shfl_xor(den0, mk);
        den1 += __shfl_xor(den1, mk);
        den2 += __shfl_xor(den2, mk);
        den3 += __shfl_xor(den3, mk);
    }

    float o0 = acc0 / (den0 + 1e-16f) + b2[lane];
    float o1 = acc1 / (den1 + 1e-16f) + b2[64 + lane];
    float o2 = acc2 / (den2 + 1e-16f) + b2[128 + lane];
    float o3 = acc3 / (den3 + 1e-16f) + b2[192 + lane];
    o0 = o0 > 0.f ? o0 : expm1f(o0);
    o1 = o1 > 0.f ? o1 : expm1f(o1);
    o2 = o2 > 0.f ? o2 : expm1f(o2);
    o3 = o3 > 0.f ? o3 : expm1f(o3);
    const float2* w32 = (const float2*)W3;     // W3[256][2]
    float2 w0 = w32[lane], w1 = w32[64 + lane];
    float2 w2 = w32[128 + lane], w3 = w32[192 + lane];
    float px = o0 * w0.x + o1 * w1.x + o2 * w2.x + o3 * w3.x;
    float py = o0 * w0.y + o1 * w1.y + o2 * w2.y + o3 * w3.y;
#pragma unroll
    for (int mk = 1; mk < 64; mk <<= 1) {
        px += __shfl_xor(px, mk);
        py += __shfl_xor(py, mk);
    }
    if (lane == 0) {
        float di = dinv[d];
        xw3[d] = make_float2(px * di, py * di);
    }
}

// ---------------- GCN2 aggregate: out = dinv[d]*sum_s xw3[s] + b3 -----------
__global__ void k_agg3(const int* __restrict__ rowptr, const int* __restrict__ col,
        const float2* __restrict__ xw3, const float* __restrict__ dinv,
        const float* __restrict__ b3, float* __restrict__ out) {
    int d = blockIdx.x * 256 + threadIdx.x;
    if (d >= N_NODES) return;
    int e = rowptr[d], end = rowptr[d + 1];
    float a0 = 0.f, a1 = 0.f;
    for (; e < end; ++e) {
        float2 v = xw3[col[e]];
        a0 += v.x; a1 += v.y;
    }
    float di = dinv[d];
    out[d * 2 + 0] = fmaf(a0, di, b3[0]);
    out[d * 2 + 1] = fmaf(a1, di, b3[1]);
}

// ---------------- launch ----------------

extern "C" void kernel_launch(void* const* d_in, const int* in_sizes, int n_in,
                              void* d_out, int out_size, void* d_ws, size_t ws_size,
                              hipStream_t stream) {
    const float* x       = (const float*)d_in[0];
    const int*   ei      = (const int*)d_in[1];
    const float* W1      = (const float*)d_in[2];
    const float* b1      = (const float*)d_in[3];
    const float* W2      = (const float*)d_in[4];
    const float* att_src = (const float*)d_in[5];
    const float* att_dst = (const float*)d_in[6];
    const float* b2      = (const float*)d_in[7];
    const float* W3      = (const float*)d_in[8];
    const float* b3      = (const float*)d_in[9];
    float* out = (float*)d_out;
    (void)in_sizes; (void)n_in; (void)out_size; (void)ws_size;

    char* ws = (char*)d_ws;
    size_t off = 0;
    auto alloc = [&](size_t bytes) -> void* {
        void* p = ws + off;
        off = (off + bytes + 255) & ~(size_t)255;
        return p;
    };
    int*    rowptr = (int*)alloc((N_NODES + 1) * sizeof(int));
    int*    cnt    = (int*)alloc(N_NODES * sizeof(int));
    int*    cur    = (int*)alloc(N_NODES * sizeof(int));
    int*    bsum   = (int*)alloc(NSB * sizeof(int));
    int*    col    = (int*)alloc((size_t)E2 * sizeof(int));
    float*  dinv   = (float*)alloc(N_NODES * sizeof(float));
    float*  wsd    = (float*)alloc(64 * 8 * sizeof(float));
    unsigned short* xw1b = (unsigned short*)alloc((size_t)N_NODES * HID * sizeof(unsigned short));
    unsigned short* h1b  = (unsigned short*)alloc((size_t)N_NODES * HID * sizeof(unsigned short));
    float*  a_s    = (float*)alloc((size_t)N_NODES * HEADS * sizeof(float));
    float*  a_d    = (float*)alloc((size_t)N_NODES * HEADS * sizeof(float));
    unsigned short* xw2b = (unsigned short*)alloc((size_t)N_NODES * HH * sizeof(unsigned short));
    float2* xw3    = (float2*)alloc((size_t)N_NODES * sizeof(float2));

    hipMemsetAsync(cnt, 0, N_NODES * sizeof(int), stream);
    k_hist<<<GFILL, 256, 0, stream>>>(ei + N_EDGES, cnt);
    k_scan1<<<NSB + 8, 256, 0, stream>>>(cnt, bsum, W2, att_src, att_dst, wsd);
    k_scan3<<<NSB, 256, 0, stream>>>(cnt, bsum, rowptr, dinv, cur, col);
    // fused: CSR fill (latency-bound) + GEMM1 (compute-bound) share the GPU
    k_fill_gemm1<<<GFILL + GGEMM1, 256, 0, stream>>>(ei, rowptr, cur, col,
                                                     x, W1, dinv, xw1b);

    k_agg1<<<(N_NODES + 3) / 4, 256, 0, stream>>>(rowptr, col, xw1b, dinv, b1, h1b);
    k_gemm2<<<N_NODES / 32, 256, 0, stream>>>(h1b, W2, wsd, xw2b, a_s, a_d);
    const int HALF = 50000;                       // nodes per half
    k_agg2<<<HALF / 4, 256, 0, stream>>>(rowptr, col, xw2b, a_s, a_d, b2, W3, dinv, xw3, 0);
    k_agg2<<<(N_NODES - HALF + 3) / 4, 256, 0, stream>>>(rowptr, col, xw2b, a_s, a_d, b2, W3, dinv, xw3, HALF);
    k_agg3<<<(N_NODES + 255) / 256, 256, 0, stream>>>(rowptr, col, xw3, dinv, b3, out);
}

// Round 10
// 540.363 us; speedup vs baseline: 1.1997x; 1.1997x over previous
//
#include <hip/hip_runtime.h>
#include <math.h>

// Problem constants (from reference)
#define N_NODES 100000
#define N_EDGES 1600000
#define E2      (N_NODES + N_EDGES)   // edges incl. self-loops = 1,700,000
#define IN_C    128
#define HID     64
#define HEADS   4
#define HH      256                    // HEADS*HID
#define OUT_C   2
#define NEG_SLOPE 0.2f

#define SB   1024                      // elements per scan block
#define NSB  ((N_NODES + SB - 1) / SB) // 98
#define NCHUNK 6250                    // fill chunks (6250*256 == N_EDGES)
#define NRANGE 8                       // dst ranges (bands of 12500 nodes)
#define RDIV   12500

__device__ __forceinline__ float bf2f(unsigned short u) {
    return __uint_as_float(((unsigned)u) << 16);
}
__device__ __forceinline__ unsigned short f2bf(float f) {
    unsigned u = __float_as_uint(f);
    u += 0x7fffu + ((u >> 16) & 1u);   // RNE
    return (unsigned short)(u >> 16);
}

// ---------------- CSR build ----------------
// cnt[] counts REAL edges only; degree = cnt+1 (self-loop at slot 0, placed
// by k_scan3). hist also emits rank[i] (edge's index within its dst segment)
// so the fill pass needs NO atomics. Fill is range-banded: blocks writing the
// same dst band are contiguous in dispatch order, so concurrent col writes
// cluster in a ~850KB slice and merge in cache instead of 1 HBM line per
// write (round 8/9: WRITE_SIZE 107MB = 64B/edge).

__global__ void k_hist(const int* __restrict__ dst, int* __restrict__ cnt,
                       int* __restrict__ rank) {
    int i = blockIdx.x * 256 + threadIdx.x;
    if (i >= N_EDGES) return;
    rank[i] = atomicAdd(&cnt[dst[i]], 1);
}

// scan1: per-block sums of (cnt+1) -> bsum[NSB]; extra 8 blocks do prews.
// wsd[k][o<4] = sum_c W2[k][o*64+c]*att_src[o*64+c]; o>=4 -> att_dst
__global__ __launch_bounds__(256) void k_scan1(const int* __restrict__ cnt,
        int* __restrict__ bsum, const float* __restrict__ W2,
        const float* __restrict__ att_src, const float* __restrict__ att_dst,
        float* __restrict__ wsd) {
    int b = blockIdx.x, t = threadIdx.x;
    if (b >= NSB) {                      // prews tail blocks
        if (t < 64) {
            int g = (b - NSB) * 64 + t;  // 0..511
            int k = g >> 3, o = g & 7;
            int h = o & 3;
            const float* att = (o < 4) ? att_src : att_dst;
            float acc = 0.f;
            const float* wrow = W2 + (size_t)k * HH + h * 64;
            const float* arow = att + h * 64;
            for (int c = 0; c < 64; ++c) acc = fmaf(wrow[c], arow[c], acc);
            wsd[k * 8 + o] = acc;
        }
        return;
    }
    int i = b * SB + t * 4;
    int s = 0;
    if (i + 3 < N_NODES) {
        int4 v = *(const int4*)(cnt + i);
        s = (v.x + v.y) + (v.z + v.w) + 4;       // +1 self-loop per node
    } else {
        for (int k = 0; k < 4; ++k) if (i + k < N_NODES) s += cnt[i + k] + 1;
    }
#pragma unroll
    for (int off = 1; off < 64; off <<= 1) s += __shfl_xor(s, off);
    __shared__ int wsum[4];
    int lane = t & 63, wv = t >> 6;
    if (lane == 0) wsum[wv] = s;
    __syncthreads();
    if (t == 0) bsum[b] = (wsum[0] + wsum[1]) + (wsum[2] + wsum[3]);
}

// scan3: block b computes prefix over bsum[0..b) itself, scans its chunk
// (deg = cnt+1), writes rowptr + dinv, pre-places self-loops at slot 0.
__global__ __launch_bounds__(256) void k_scan3(const int* __restrict__ cnt,
        const int* __restrict__ bsum, int* __restrict__ rowptr,
        float* __restrict__ dinv, int* __restrict__ col) {
    int b = blockIdx.x, t = threadIdx.x;
    int lane = t & 63, wv = t >> 6;
    __shared__ int wred[4];
    {
        int v = (t < b) ? bsum[t] : 0;   // b <= 98 <= 256
#pragma unroll
        for (int off = 1; off < 64; off <<= 1) v += __shfl_xor(v, off);
        if (lane == 0) wred[wv] = v;
    }
    __syncthreads();
    int pre = (wred[0] + wred[1]) + (wred[2] + wred[3]);
    __syncthreads();

    int i = b * SB + t * 4;
    int c0 = 0, c1 = 0, c2 = 0, c3 = 0;
    if (i + 3 < N_NODES) {
        int4 v = *(const int4*)(cnt + i);
        c0 = v.x; c1 = v.y; c2 = v.z; c3 = v.w;
    } else if (i < N_NODES) {
        c0 = cnt[i];
        if (i + 1 < N_NODES) c1 = cnt[i + 1];
        if (i + 2 < N_NODES) c2 = cnt[i + 2];
    }
    int n0 = (i < N_NODES), n1 = (i + 1 < N_NODES),
        n2 = (i + 2 < N_NODES), n3 = (i + 3 < N_NODES);
    int d0 = c0 + n0, d1 = c1 + n1, d2 = c2 + n2, d3 = c3 + n3;  // degrees
    int s = (d0 + d1) + (d2 + d3);
    int inc = s;
#pragma unroll
    for (int off = 1; off < 64; off <<= 1) {
        int u = __shfl_up(inc, off);
        if (lane >= off) inc += u;
    }
    __shared__ int wtot[4];
    if (lane == 63) wtot[wv] = inc;
    __syncthreads();
    int base = pre + (inc - s);
    for (int w = 0; w < wv; ++w) base += wtot[w];
    if (n0) { rowptr[i]     = base;                dinv[i]     = rsqrtf((float)d0); col[base] = i; }
    if (n1) { rowptr[i + 1] = base + d0;           dinv[i + 1] = rsqrtf((float)d1); col[base + d0] = i + 1; }
    if (n2) { rowptr[i + 2] = base + d0 + d1;      dinv[i + 2] = rsqrtf((float)d2); col[base + d0 + d1] = i + 2; }
    if (n3) { rowptr[i + 3] = base + d0 + d1 + d2; dinv[i + 3] = rsqrtf((float)d3); col[base + d0 + d1 + d2] = i + 3; }
    if (b == 0 && t == 0) rowptr[N_NODES] = E2;
}

// fill: atomic-free banded scatter. range = blockIdx/NCHUNK so all blocks of
// one dst band are contiguous in dispatch order -> col writes cluster.
__global__ void k_fill(const int* __restrict__ ei, const int* __restrict__ rowptr,
                       const int* __restrict__ rank, int* __restrict__ col) {
    int r = blockIdx.x / NCHUNK;
    int c = blockIdx.x - r * NCHUNK;
    int i = c * 256 + threadIdx.x;          // NCHUNK*256 == N_EDGES exactly
    int d = ei[N_EDGES + i];
    if (d / RDIV != r) return;
    col[rowptr[d] + 1 + rank[i]] = ei[i];   // slot 0 = self-loop
}

// ---------------- GEMM1: xw1b = bf16((x @ W1) * dinv[row])  [N,64] ----------
__global__ __launch_bounds__(256) void k_gemm1(const float* __restrict__ x,
        const float* __restrict__ W1, const float* __restrict__ dinv,
        unsigned short* __restrict__ xw1b) {
    __shared__ float xs[32 * IN_C];  // 16 KB
    int t = threadIdx.x;
    int r0 = blockIdx.x * 32;        // grid = N/32, exact
    const float4* xg = (const float4*)(x + (size_t)r0 * IN_C);
    float4* xs4 = (float4*)xs;
#pragma unroll
    for (int i = 0; i < 4; ++i) xs4[i * 256 + t] = xg[i * 256 + t];
    int lane = t & 63, wv = t >> 6;
    float w[IN_C];
#pragma unroll
    for (int k = 0; k < IN_C; ++k) w[k] = W1[k * HID + lane];
    __syncthreads();
    for (int j0 = 0; j0 < 8; j0 += 2) {
        int ja = wv * 8 + j0, jb = ja + 1;
        const float4* xa = (const float4*)(xs + ja * IN_C);
        const float4* xb = (const float4*)(xs + jb * IN_C);
        float aA = 0.f, aB = 0.f;
#pragma unroll
        for (int kk = 0; kk < 32; ++kk) {
            float4 va = xa[kk], vb = xb[kk];
            aA = fmaf(va.x, w[4 * kk + 0], aA);
            aA = fmaf(va.y, w[4 * kk + 1], aA);
            aA = fmaf(va.z, w[4 * kk + 2], aA);
            aA = fmaf(va.w, w[4 * kk + 3], aA);
            aB = fmaf(vb.x, w[4 * kk + 0], aB);
            aB = fmaf(vb.y, w[4 * kk + 1], aB);
            aB = fmaf(vb.z, w[4 * kk + 2], aB);
            aB = fmaf(vb.w, w[4 * kk + 3], aB);
        }
        int ra = r0 + ja, rb = r0 + jb;
        xw1b[(size_t)ra * HID + lane] = f2bf(aA * dinv[ra]);
        xw1b[(size_t)rb * HID + lane] = f2bf(aB * dinv[rb]);
    }
}

// ---------------- GCN1 aggregate: h1b = bf16(relu(dinv*sum + b1)) -----------
// wave per dst; 16 lanes per edge (ushort4 = 4 bf16 ch/lane), 4 edges/group.
__global__ __launch_bounds__(256) void k_agg1(const int* __restrict__ rowptr,
        const int* __restrict__ col, const unsigned short* __restrict__ xw1b,
        const float* __restrict__ dinv, const float* __restrict__ b1,
        unsigned short* __restrict__ h1b) {
    int t = threadIdx.x;
    int lane = t & 63;
    int d = blockIdx.x * 4 + (t >> 6);
    if (d >= N_NODES) return;
    int start = rowptr[d], end = rowptr[d + 1];
    int sub = lane >> 4;       // which of 4 edges in a group
    int cpos = lane & 15;      // channel quad (4 bf16)
    float4 acc = make_float4(0.f, 0.f, 0.f, 0.f);
    for (int base = start; base < end; base += 64) {
        int cnt = min(64, end - base);
        int sl = (base + lane < end) ? col[base + lane] : 0;
#pragma unroll 2
        for (int j = 0; j < cnt; j += 4) {
            int idx = j + sub;
            int sj = __shfl(sl, idx);
            if (idx < cnt) {
                ushort4 v = ((const ushort4*)(xw1b + (size_t)sj * HID))[cpos];
                acc.x += bf2f(v.x); acc.y += bf2f(v.y);
                acc.z += bf2f(v.z); acc.w += bf2f(v.w);
            }
        }
    }
    acc.x += __shfl_xor(acc.x, 16); acc.y += __shfl_xor(acc.y, 16);
    acc.z += __shfl_xor(acc.z, 16); acc.w += __shfl_xor(acc.w, 16);
    acc.x += __shfl_xor(acc.x, 32); acc.y += __shfl_xor(acc.y, 32);
    acc.z += __shfl_xor(acc.z, 32); acc.w += __shfl_xor(acc.w, 32);
    if (lane < 16) {
        float di = dinv[d];
        float4 b = ((const float4*)b1)[lane];
        float ox = fmaf(acc.x, di, b.x); ox = ox > 0.f ? ox : 0.f;
        float oy = fmaf(acc.y, di, b.y); oy = oy > 0.f ? oy : 0.f;
        float oz = fmaf(acc.z, di, b.z); oz = oz > 0.f ? oz : 0.f;
        float ow = fmaf(acc.w, di, b.w); ow = ow > 0.f ? ow : 0.f;
        ushort4 o = make_ushort4(f2bf(ox), f2bf(oy), f2bf(oz), f2bf(ow));
        ((ushort4*)(h1b + (size_t)d * HID))[lane] = o;
    }
}

// ---------------- GEMM2: xw2b = bf16(h1 @ W2) [n][c*4+h], a_s, a_d ----------
__global__ __launch_bounds__(256) void k_gemm2(const unsigned short* __restrict__ h1b,
        const float* __restrict__ W2, const float* __restrict__ wsd,
        unsigned short* __restrict__ xw2b, float* __restrict__ a_s,
        float* __restrict__ a_d) {
    __shared__ float hs[32 * HID];   // 8 KB (fp32, converted at stage-in)
    __shared__ float ws[512];        // 2 KB
    int t = threadIdx.x;
    int r0 = blockIdx.x * 32;        // grid = N/32, exact
    const ushort4* hg = (const ushort4*)(h1b + (size_t)r0 * HID);  // 512 total
#pragma unroll
    for (int i = 0; i < 2; ++i) {
        ushort4 v = hg[i * 256 + t];
        ((float4*)hs)[i * 256 + t] =
            make_float4(bf2f(v.x), bf2f(v.y), bf2f(v.z), bf2f(v.w));
    }
    ((float2*)ws)[t] = ((const float2*)wsd)[t];
    float w[HID];
#pragma unroll
    for (int k = 0; k < HID; ++k) w[k] = W2[k * HH + t];
    __syncthreads();
    int lane = t & 63, h = t >> 6;
    for (int j = 0; j < 32; j += 2) {
        const float4* ha = (const float4*)(hs + j * HID);
        const float4* hb = (const float4*)(hs + (j + 1) * HID);
        float aA = 0.f, aB = 0.f;
#pragma unroll
        for (int kk = 0; kk < 16; ++kk) {
            float4 va = ha[kk], vb = hb[kk];
            aA = fmaf(va.x, w[4 * kk + 0], aA);
            aA = fmaf(va.y, w[4 * kk + 1], aA);
            aA = fmaf(va.z, w[4 * kk + 2], aA);
            aA = fmaf(va.w, w[4 * kk + 3], aA);
            aB = fmaf(vb.x, w[4 * kk + 0], aB);
            aB = fmaf(vb.y, w[4 * kk + 1], aB);
            aB = fmaf(vb.z, w[4 * kk + 2], aB);
            aB = fmaf(vb.w, w[4 * kk + 3], aB);
        }
        xw2b[(size_t)(r0 + j) * HH + lane * 4 + h] = f2bf(aA);
        xw2b[(size_t)(r0 + j + 1) * HH + lane * 4 + h] = f2bf(aB);
    }
    {
        int j = t >> 3, o = t & 7;
        const float* hrow = hs + j * HID;
        float acc = 0.f;
#pragma unroll
        for (int k = 0; k < 64; ++k) {
            int ke = (k + j) & 63;
            acc = fmaf(hrow[ke], ws[ke * 8 + o], acc);
        }
        int r = r0 + j;
        if (o < 4) a_s[r * 4 + o] = acc;
        else       a_d[r * 4 + (o - 4)] = acc;
    }
}

// ---------------- GAT aggregate + ELU + fused GEMM3 -------------------------
// unroll 4: unroll 8 raised VGPR 32->48, occupancy 79->48%, dur +14% (round 5)
// TWO half-range dispatches: keeps sub-max kernels visible in the top-5
// profile window (the window only ever shows the global max dispatch).
__global__ __launch_bounds__(256) void k_agg2(const int* __restrict__ rowptr,
        const int* __restrict__ col, const unsigned short* __restrict__ xw2b,
        const float* __restrict__ a_s, const float* __restrict__ a_d,
        const float* __restrict__ b2, const float* __restrict__ W3,
        const float* __restrict__ dinv, float2* __restrict__ xw3, int dbase) {
    __shared__ int   ss[4][64];      // 1 KB
    __shared__ float sp[4][64][4];   // 4 KB
    int t = threadIdx.x;
    int lane = t & 63, wv = t >> 6;
    int d = dbase + blockIdx.x * 4 + wv;
    if (d >= N_NODES) return;
    const float4* as4 = (const float4*)a_s;
    float4 adv = ((const float4*)a_d)[d];
    int start = rowptr[d], end = rowptr[d + 1];

    float den0 = 0.f, den1 = 0.f, den2 = 0.f, den3 = 0.f;
    float acc0 = 0.f, acc1 = 0.f, acc2 = 0.f, acc3 = 0.f;
    const ushort4* xw24 = (const ushort4*)xw2b;      // row = 64 ushort4
    for (int base = start; base < end; base += 64) {
        int cnt = min(64, end - base);
        float p0 = 0.f, p1 = 0.f, p2 = 0.f, p3 = 0.f;
        int s = 0;
        if (lane < cnt) {
            s = col[base + lane];
            float4 av = as4[s];
            float v;
            v = av.x + adv.x; v = v > 0.f ? v : NEG_SLOPE * v; p0 = __expf(v);
            v = av.y + adv.y; v = v > 0.f ? v : NEG_SLOPE * v; p1 = __expf(v);
            v = av.z + adv.z; v = v > 0.f ? v : NEG_SLOPE * v; p2 = __expf(v);
            v = av.w + adv.w; v = v > 0.f ? v : NEG_SLOPE * v; p3 = __expf(v);
            den0 += p0; den1 += p1; den2 += p2; den3 += p3;
        }
        ss[wv][lane] = s;                                  // wave-private LDS
        ((float4*)sp[wv])[lane] = make_float4(p0, p1, p2, p3);
#pragma unroll 4
        for (int j = 0; j < cnt; ++j) {
            int sj = ss[wv][j];                            // broadcast read
            float4 pj = ((const float4*)sp[wv])[j];        // broadcast read
            ushort4 xv = xw24[(size_t)sj * 64 + lane];     // 8B/lane coalesced
            acc0 = fmaf(pj.x, bf2f(xv.x), acc0);
            acc1 = fmaf(pj.y, bf2f(xv.y), acc1);
            acc2 = fmaf(pj.z, bf2f(xv.z), acc2);
            acc3 = fmaf(pj.w, bf2f(xv.w), acc3);
        }
    }
#pragma unroll
    for (int mk = 1; mk < 64; mk <<= 1) {
        den0 += __shfl_xor(den0, mk);
        den1 += __shfl_xor(den1, mk);
        den2 += __shfl_xor(den2, mk);
        den3 += __shfl_xor(den3, mk);
    }

    float o0 = acc0 / (den0 + 1e-16f) + b2[lane];
    float o1 = acc1 / (den1 + 1e-16f) + b2[64 + lane];
    float o2 = acc2 / (den2 + 1e-16f) + b2[128 + lane];
    float o3 = acc3 / (den3 + 1e-16f) + b2[192 + lane];
    o0 = o0 > 0.f ? o0 : expm1f(o0);
    o1 = o1 > 0.f ? o1 : expm1f(o1);
    o2 = o2 > 0.f ? o2 : expm1f(o2);
    o3 = o3 > 0.f ? o3 : expm1f(o3);
    const float2* w32 = (const float2*)W3;     // W3[256][2]
    float2 w0 = w32[lane], w1 = w32[64 + lane];
    float2 w2 = w32[128 + lane], w3 = w32[192 + lane];
    float px = o0 * w0.x + o1 * w1.x + o2 * w2.x + o3 * w3.x;
    float py = o0 * w0.y + o1 * w1.y + o2 * w2.y + o3 * w3.y;
#pragma unroll
    for (int mk = 1; mk < 64; mk <<= 1) {
        px += __shfl_xor(px, mk);
        py += __shfl_xor(py, mk);
    }
    if (lane == 0) {
        float di = dinv[d];
        xw3[d] = make_float2(px * di, py * di);
    }
}

// ---------------- GCN2 aggregate: out = dinv[d]*sum_s xw3[s] + b3 -----------
__global__ void k_agg3(const int* __restrict__ rowptr, const int* __restrict__ col,
        const float2* __restrict__ xw3, const float* __restrict__ dinv,
        const float* __restrict__ b3, float* __restrict__ out) {
    int d = blockIdx.x * 256 + threadIdx.x;
    if (d >= N_NODES) return;
    int e = rowptr[d], end = rowptr[d + 1];
    float a0 = 0.f, a1 = 0.f;
    for (; e < end; ++e) {
        float2 v = xw3[col[e]];
        a0 += v.x; a1 += v.y;
    }
    float di = dinv[d];
    out[d * 2 + 0] = fmaf(a0, di, b3[0]);
    out[d * 2 + 1] = fmaf(a1, di, b3[1]);
}

// ---------------- launch ----------------

extern "C" void kernel_launch(void* const* d_in, const int* in_sizes, int n_in,
                              void* d_out, int out_size, void* d_ws, size_t ws_size,
                              hipStream_t stream) {
    const float* x       = (const float*)d_in[0];
    const int*   ei      = (const int*)d_in[1];
    const float* W1      = (const float*)d_in[2];
    const float* b1      = (const float*)d_in[3];
    const float* W2      = (const float*)d_in[4];
    const float* att_src = (const float*)d_in[5];
    const float* att_dst = (const float*)d_in[6];
    const float* b2      = (const float*)d_in[7];
    const float* W3      = (const float*)d_in[8];
    const float* b3      = (const float*)d_in[9];
    float* out = (float*)d_out;
    (void)in_sizes; (void)n_in; (void)out_size; (void)ws_size;

    char* ws = (char*)d_ws;
    size_t off = 0;
    auto alloc = [&](size_t bytes) -> void* {
        void* p = ws + off;
        off = (off + bytes + 255) & ~(size_t)255;
        return p;
    };
    int*    rowptr = (int*)alloc((N_NODES + 1) * sizeof(int));
    int*    cnt    = (int*)alloc(N_NODES * sizeof(int));
    int*    bsum   = (int*)alloc(NSB * sizeof(int));
    int*    rank   = (int*)alloc((size_t)N_EDGES * sizeof(int));
    int*    col    = (int*)alloc((size_t)E2 * sizeof(int));
    float*  dinv   = (float*)alloc(N_NODES * sizeof(float));
    float*  wsd    = (float*)alloc(64 * 8 * sizeof(float));
    unsigned short* xw1b = (unsigned short*)alloc((size_t)N_NODES * HID * sizeof(unsigned short));
    unsigned short* h1b  = (unsigned short*)alloc((size_t)N_NODES * HID * sizeof(unsigned short));
    float*  a_s    = (float*)alloc((size_t)N_NODES * HEADS * sizeof(float));
    float*  a_d    = (float*)alloc((size_t)N_NODES * HEADS * sizeof(float));
    unsigned short* xw2b = (unsigned short*)alloc((size_t)N_NODES * HH * sizeof(unsigned short));
    float2* xw3    = (float2*)alloc((size_t)N_NODES * sizeof(float2));

    hipMemsetAsync(cnt, 0, N_NODES * sizeof(int), stream);
    k_hist<<<NCHUNK, 256, 0, stream>>>(ei + N_EDGES, cnt, rank);
    k_scan1<<<NSB + 8, 256, 0, stream>>>(cnt, bsum, W2, att_src, att_dst, wsd);
    k_scan3<<<NSB, 256, 0, stream>>>(cnt, bsum, rowptr, dinv, col);
    k_fill<<<NCHUNK * NRANGE, 256, 0, stream>>>(ei, rowptr, rank, col);

    k_gemm1<<<N_NODES / 32, 256, 0, stream>>>(x, W1, dinv, xw1b);
    k_agg1<<<(N_NODES + 3) / 4, 256, 0, stream>>>(rowptr, col, xw1b, dinv, b1, h1b);
    k_gemm2<<<N_NODES / 32, 256, 0, stream>>>(h1b, W2, wsd, xw2b, a_s, a_d);
    const int HALF = 50000;                       // nodes per half
    k_agg2<<<HALF / 4, 256, 0, stream>>>(rowptr, col, xw2b, a_s, a_d, b2, W3, dinv, xw3, 0);
    k_agg2<<<(N_NODES - HALF + 3) / 4, 256, 0, stream>>>(rowptr, col, xw2b, a_s, a_d, b2, W3, dinv, xw3, HALF);
    k_agg3<<<(N_NODES + 255) / 256, 256, 0, stream>>>(rowptr, col, xw3, dinv, b3, out);
}

// Round 11
// 489.463 us; speedup vs baseline: 1.3245x; 1.1040x over previous
//
#include <hip/hip_runtime.h>
#include <math.h>

// Problem constants (from reference)
#define N_NODES 100000
#define N_EDGES 1600000
#define E2      (N_NODES + N_EDGES)   // edges incl. self-loops = 1,700,000
#define IN_C    128
#define HID     64
#define HEADS   4
#define HH      256                    // HEADS*HID
#define OUT_C   2
#define NEG_SLOPE 0.2f

#define SB   1024                      // elements per scan block
#define NSB  ((N_NODES + SB - 1) / SB) // 98
#define NCHUNK 6250                    // fill chunks (6250*256 == N_EDGES)
#define NRANGE 8                       // dst ranges (bands of 12500 nodes)
#define RDIV   12500
#define RT     10                      // row-tiles (16 rows) per gemm2m block

typedef __attribute__((ext_vector_type(8))) short bf16x8;
typedef __attribute__((ext_vector_type(4))) float f32x4;

__device__ __forceinline__ float bf2f(unsigned short u) {
    return __uint_as_float(((unsigned)u) << 16);
}
__device__ __forceinline__ unsigned short f2bf(float f) {
    unsigned u = __float_as_uint(f);
    u += 0x7fffu + ((u >> 16) & 1u);   // RNE
    return (unsigned short)(u >> 16);
}

// ---------------- CSR build ----------------
// cnt[] counts REAL edges only; degree = cnt+1 (self-loop at slot 0, placed
// by k_scan3). hist emits rank[i] so fill needs NO atomics. Fill is
// range-banded: blocks writing one dst band are contiguous in dispatch order
// so col writes cluster and merge in cache (round 10: fixed the 64B/edge
// writeback, WRITE 107MB -> merged).

__global__ void k_hist(const int* __restrict__ dst, int* __restrict__ cnt,
                       int* __restrict__ rank) {
    int i = blockIdx.x * 256 + threadIdx.x;
    if (i >= N_EDGES) return;
    rank[i] = atomicAdd(&cnt[dst[i]], 1);
}

// prep: W2t[n*64+k] = bf16(W2[k][n]) (B^T for MFMA); wsdt[o*64+k] =
// bf16(sum_c W2[k][o_head*64+c]*att[o_head][c]), cols 8..15 zero-padded.
__global__ __launch_bounds__(256) void k_prep(const float* __restrict__ W2,
        const float* __restrict__ att_src, const float* __restrict__ att_dst,
        unsigned short* __restrict__ W2t, unsigned short* __restrict__ wsdt) {
    int b = blockIdx.x, t = threadIdx.x;
    if (b < 64) {
        int g = b * 256 + t;           // g = k*256 + n, coalesced W2 read
        int k = g >> 8, n = g & 255;
        W2t[n * 64 + k] = f2bf(W2[g]);
        return;
    }
    int g = (b - 64) * 256 + t;        // 0..511
    wsdt[512 + g] = 0;                 // pad cols 8..15
    int k = g >> 3, o = g & 7;
    int h = o & 3;
    const float* att = (o < 4) ? att_src : att_dst;
    float acc = 0.f;
    const float* wrow = W2 + (size_t)k * HH + h * 64;
    const float* arow = att + h * 64;
    for (int c = 0; c < 64; ++c) acc = fmaf(wrow[c], arow[c], acc);
    wsdt[o * 64 + k] = f2bf(acc);
}

// scan1: per-block sums of (cnt+1) -> bsum[NSB]
__global__ __launch_bounds__(256) void k_scan1(const int* __restrict__ cnt,
                                               int* __restrict__ bsum) {
    int b = blockIdx.x, t = threadIdx.x;
    int i = b * SB + t * 4;
    int s = 0;
    if (i + 3 < N_NODES) {
        int4 v = *(const int4*)(cnt + i);
        s = (v.x + v.y) + (v.z + v.w) + 4;       // +1 self-loop per node
    } else {
        for (int k = 0; k < 4; ++k) if (i + k < N_NODES) s += cnt[i + k] + 1;
    }
#pragma unroll
    for (int off = 1; off < 64; off <<= 1) s += __shfl_xor(s, off);
    __shared__ int wsum[4];
    int lane = t & 63, wv = t >> 6;
    if (lane == 0) wsum[wv] = s;
    __syncthreads();
    if (t == 0) bsum[b] = (wsum[0] + wsum[1]) + (wsum[2] + wsum[3]);
}

// scan3: block b computes prefix over bsum[0..b) itself, scans its chunk
// (deg = cnt+1), writes rowptr + dinv, pre-places self-loops at slot 0.
__global__ __launch_bounds__(256) void k_scan3(const int* __restrict__ cnt,
        const int* __restrict__ bsum, int* __restrict__ rowptr,
        float* __restrict__ dinv, int* __restrict__ col) {
    int b = blockIdx.x, t = threadIdx.x;
    int lane = t & 63, wv = t >> 6;
    __shared__ int wred[4];
    {
        int v = (t < b) ? bsum[t] : 0;   // b <= 98 <= 256
#pragma unroll
        for (int off = 1; off < 64; off <<= 1) v += __shfl_xor(v, off);
        if (lane == 0) wred[wv] = v;
    }
    __syncthreads();
    int pre = (wred[0] + wred[1]) + (wred[2] + wred[3]);
    __syncthreads();

    int i = b * SB + t * 4;
    int c0 = 0, c1 = 0, c2 = 0, c3 = 0;
    if (i + 3 < N_NODES) {
        int4 v = *(const int4*)(cnt + i);
        c0 = v.x; c1 = v.y; c2 = v.z; c3 = v.w;
    } else if (i < N_NODES) {
        c0 = cnt[i];
        if (i + 1 < N_NODES) c1 = cnt[i + 1];
        if (i + 2 < N_NODES) c2 = cnt[i + 2];
    }
    int n0 = (i < N_NODES), n1 = (i + 1 < N_NODES),
        n2 = (i + 2 < N_NODES), n3 = (i + 3 < N_NODES);
    int d0 = c0 + n0, d1 = c1 + n1, d2 = c2 + n2, d3 = c3 + n3;  // degrees
    int s = (d0 + d1) + (d2 + d3);
    int inc = s;
#pragma unroll
    for (int off = 1; off < 64; off <<= 1) {
        int u = __shfl_up(inc, off);
        if (lane >= off) inc += u;
    }
    __shared__ int wtot[4];
    if (lane == 63) wtot[wv] = inc;
    __syncthreads();
    int base = pre + (inc - s);
    for (int w = 0; w < wv; ++w) base += wtot[w];
    if (n0) { rowptr[i]     = base;                dinv[i]     = rsqrtf((float)d0); col[base] = i; }
    if (n1) { rowptr[i + 1] = base + d0;           dinv[i + 1] = rsqrtf((float)d1); col[base + d0] = i + 1; }
    if (n2) { rowptr[i + 2] = base + d0 + d1;      dinv[i + 2] = rsqrtf((float)d2); col[base + d0 + d1] = i + 2; }
    if (n3) { rowptr[i + 3] = base + d0 + d1 + d2; dinv[i + 3] = rsqrtf((float)d3); col[base + d0 + d1 + d2] = i + 3; }
    if (b == 0 && t == 0) rowptr[N_NODES] = E2;
}

// fill: atomic-free banded scatter.
__global__ void k_fill(const int* __restrict__ ei, const int* __restrict__ rowptr,
                       const int* __restrict__ rank, int* __restrict__ col) {
    int r = blockIdx.x / NCHUNK;
    int c = blockIdx.x - r * NCHUNK;
    int i = c * 256 + threadIdx.x;          // NCHUNK*256 == N_EDGES exactly
    int d = ei[N_EDGES + i];
    if (d / RDIV != r) return;
    col[rowptr[d] + 1 + rank[i]] = ei[i];   // slot 0 = self-loop
}

// ---------------- GEMM1: xw1b = bf16((x @ W1) * dinv[row])  [N,64] ----------
__global__ __launch_bounds__(256) void k_gemm1(const float* __restrict__ x,
        const float* __restrict__ W1, const float* __restrict__ dinv,
        unsigned short* __restrict__ xw1b) {
    __shared__ float xs[32 * IN_C];  // 16 KB
    int t = threadIdx.x;
    int r0 = blockIdx.x * 32;        // grid = N/32, exact
    const float4* xg = (const float4*)(x + (size_t)r0 * IN_C);
    float4* xs4 = (float4*)xs;
#pragma unroll
    for (int i = 0; i < 4; ++i) xs4[i * 256 + t] = xg[i * 256 + t];
    int lane = t & 63, wv = t >> 6;
    float w[IN_C];
#pragma unroll
    for (int k = 0; k < IN_C; ++k) w[k] = W1[k * HID + lane];
    __syncthreads();
    for (int j0 = 0; j0 < 8; j0 += 2) {
        int ja = wv * 8 + j0, jb = ja + 1;
        const float4* xa = (const float4*)(xs + ja * IN_C);
        const float4* xb = (const float4*)(xs + jb * IN_C);
        float aA = 0.f, aB = 0.f;
#pragma unroll
        for (int kk = 0; kk < 32; ++kk) {
            float4 va = xa[kk], vb = xb[kk];
            aA = fmaf(va.x, w[4 * kk + 0], aA);
            aA = fmaf(va.y, w[4 * kk + 1], aA);
            aA = fmaf(va.z, w[4 * kk + 2], aA);
            aA = fmaf(va.w, w[4 * kk + 3], aA);
            aB = fmaf(vb.x, w[4 * kk + 0], aB);
            aB = fmaf(vb.y, w[4 * kk + 1], aB);
            aB = fmaf(vb.z, w[4 * kk + 2], aB);
            aB = fmaf(vb.w, w[4 * kk + 3], aB);
        }
        int ra = r0 + ja, rb = r0 + jb;
        xw1b[(size_t)ra * HID + lane] = f2bf(aA * dinv[ra]);
        xw1b[(size_t)rb * HID + lane] = f2bf(aB * dinv[rb]);
    }
}

// ---------------- GCN1 aggregate: h1b = bf16(relu(dinv*sum + b1)) -----------
__global__ __launch_bounds__(256) void k_agg1(const int* __restrict__ rowptr,
        const int* __restrict__ col, const unsigned short* __restrict__ xw1b,
        const float* __restrict__ dinv, const float* __restrict__ b1,
        unsigned short* __restrict__ h1b) {
    int t = threadIdx.x;
    int lane = t & 63;
    int d = blockIdx.x * 4 + (t >> 6);
    if (d >= N_NODES) return;
    int start = rowptr[d], end = rowptr[d + 1];
    int sub = lane >> 4;       // which of 4 edges in a group
    int cpos = lane & 15;      // channel quad (4 bf16)
    float4 acc = make_float4(0.f, 0.f, 0.f, 0.f);
    for (int base = start; base < end; base += 64) {
        int cnt = min(64, end - base);
        int sl = (base + lane < end) ? col[base + lane] : 0;
#pragma unroll 2
        for (int j = 0; j < cnt; j += 4) {
            int idx = j + sub;
            int sj = __shfl(sl, idx);
            if (idx < cnt) {
                ushort4 v = ((const ushort4*)(xw1b + (size_t)sj * HID))[cpos];
                acc.x += bf2f(v.x); acc.y += bf2f(v.y);
                acc.z += bf2f(v.z); acc.w += bf2f(v.w);
            }
        }
    }
    acc.x += __shfl_xor(acc.x, 16); acc.y += __shfl_xor(acc.y, 16);
    acc.z += __shfl_xor(acc.z, 16); acc.w += __shfl_xor(acc.w, 16);
    acc.x += __shfl_xor(acc.x, 32); acc.y += __shfl_xor(acc.y, 32);
    acc.z += __shfl_xor(acc.z, 32); acc.w += __shfl_xor(acc.w, 32);
    if (lane < 16) {
        float di = dinv[d];
        float4 b = ((const float4*)b1)[lane];
        float ox = fmaf(acc.x, di, b.x); ox = ox > 0.f ? ox : 0.f;
        float oy = fmaf(acc.y, di, b.y); oy = oy > 0.f ? oy : 0.f;
        float oz = fmaf(acc.z, di, b.z); oz = oz > 0.f ? oz : 0.f;
        float ow = fmaf(acc.w, di, b.w); ow = ow > 0.f ? ow : 0.f;
        ushort4 o = make_ushort4(f2bf(ox), f2bf(oy), f2bf(oz), f2bf(ow));
        ((ushort4*)(h1b + (size_t)d * HID))[lane] = o;
    }
}

// ---------------- GEMM2 via MFMA: xw2b, a_s, a_d ----------------------------
// D = h1[128..] @ W2: M-tiles of 16, wave wv owns cols [wv*64, wv*64+64).
// A-frag: A[m=lane&15][k=quad*8+j] straight from h1b (bf16 row-major).
// B-frag: rows of W2t (= W2^T bf16), same load shape (gemm_bt pattern).
// C/D: col=lane&15, row=quad*4+reg (m89-verified). No LDS; B-frags persist
// in VGPRs across the row-tile loop. Wave 0 additionally multiplies by wsdt
// to produce attention logits a_s/a_d.
__global__ __launch_bounds__(256) void k_gemm2m(
        const unsigned short* __restrict__ h1b,
        const unsigned short* __restrict__ W2t,
        const unsigned short* __restrict__ wsdt,
        unsigned short* __restrict__ xw2b,
        float* __restrict__ a_s, float* __restrict__ a_d) {
    int t = threadIdx.x;
    int lane = t & 63, wv = t >> 6;
    int m = lane & 15, quad = lane >> 4;
    int nb = wv * 64 + m;            // this lane's base output column
    bf16x8 B[4][2];
#pragma unroll
    for (int ct = 0; ct < 4; ++ct)
#pragma unroll
        for (int ks = 0; ks < 2; ++ks)
            B[ct][ks] = *(const bf16x8*)(W2t + (size_t)(nb + ct * 16) * 64
                                         + ks * 32 + quad * 8);
    bf16x8 Bw0 = *(const bf16x8*)(wsdt + (size_t)m * 64 + quad * 8);
    bf16x8 Bw1 = *(const bf16x8*)(wsdt + (size_t)m * 64 + 32 + quad * 8);

    int r0 = blockIdx.x * (RT * 16);
    for (int tile = 0; tile < RT; ++tile) {
        int rbase = r0 + tile * 16;
        const unsigned short* ap = h1b + (size_t)(rbase + m) * 64 + quad * 8;
        bf16x8 a0 = *(const bf16x8*)(ap);
        bf16x8 a1 = *(const bf16x8*)(ap + 32);
        f32x4 c0 = {0.f, 0.f, 0.f, 0.f}, c1 = c0, c2 = c0, c3 = c0;
        c0 = __builtin_amdgcn_mfma_f32_16x16x32_bf16(a0, B[0][0], c0, 0, 0, 0);
        c1 = __builtin_amdgcn_mfma_f32_16x16x32_bf16(a0, B[1][0], c1, 0, 0, 0);
        c2 = __builtin_amdgcn_mfma_f32_16x16x32_bf16(a0, B[2][0], c2, 0, 0, 0);
        c3 = __builtin_amdgcn_mfma_f32_16x16x32_bf16(a0, B[3][0], c3, 0, 0, 0);
        c0 = __builtin_amdgcn_mfma_f32_16x16x32_bf16(a1, B[0][1], c0, 0, 0, 0);
        c1 = __builtin_amdgcn_mfma_f32_16x16x32_bf16(a1, B[1][1], c1, 0, 0, 0);
        c2 = __builtin_amdgcn_mfma_f32_16x16x32_bf16(a1, B[2][1], c2, 0, 0, 0);
        c3 = __builtin_amdgcn_mfma_f32_16x16x32_bf16(a1, B[3][1], c3, 0, 0, 0);
        int row = rbase + quad * 4;
        // interleaved layout xw2b[r][c*4+h] with n = h*64+c
#pragma unroll
        for (int ct = 0; ct < 4; ++ct) {
            int n = nb + ct * 16;
            unsigned short* p = xw2b + (size_t)row * HH + (n & 63) * 4 + (n >> 6);
            f32x4 c = (ct == 0) ? c0 : (ct == 1) ? c1 : (ct == 2) ? c2 : c3;
            p[0]       = f2bf(c[0]);
            p[HH]      = f2bf(c[1]);
            p[2 * HH]  = f2bf(c[2]);
            p[3 * HH]  = f2bf(c[3]);
        }
        if (wv == 0) {
            f32x4 aw = {0.f, 0.f, 0.f, 0.f};
            aw = __builtin_amdgcn_mfma_f32_16x16x32_bf16(a0, Bw0, aw, 0, 0, 0);
            aw = __builtin_amdgcn_mfma_f32_16x16x32_bf16(a1, Bw1, aw, 0, 0, 0);
            if (m < 4) {
#pragma unroll
                for (int r = 0; r < 4; ++r) a_s[(row + r) * 4 + m] = aw[r];
            } else if (m < 8) {
#pragma unroll
                for (int r = 0; r < 4; ++r) a_d[(row + r) * 4 + (m - 4)] = aw[r];
            }
        }
    }
}

// ---------------- GAT aggregate + ELU + fused GEMM3 -------------------------
// unroll 4: unroll 8 raised VGPR 32->48, occupancy 79->48%, dur +14% (round 5)
// TWO half-range dispatches: keeps sub-max kernels visible in the top-5
// profile window (the window only ever shows the global max dispatch).
__global__ __launch_bounds__(256) void k_agg2(const int* __restrict__ rowptr,
        const int* __restrict__ col, const unsigned short* __restrict__ xw2b,
        const float* __restrict__ a_s, const float* __restrict__ a_d,
        const float* __restrict__ b2, const float* __restrict__ W3,
        const float* __restrict__ dinv, float2* __restrict__ xw3, int dbase) {
    __shared__ int   ss[4][64];      // 1 KB
    __shared__ float sp[4][64][4];   // 4 KB
    int t = threadIdx.x;
    int lane = t & 63, wv = t >> 6;
    int d = dbase + blockIdx.x * 4 + wv;
    if (d >= N_NODES) return;
    const float4* as4 = (const float4*)a_s;
    float4 adv = ((const float4*)a_d)[d];
    int start = rowptr[d], end = rowptr[d + 1];

    float den0 = 0.f, den1 = 0.f, den2 = 0.f, den3 = 0.f;
    float acc0 = 0.f, acc1 = 0.f, acc2 = 0.f, acc3 = 0.f;
    const ushort4* xw24 = (const ushort4*)xw2b;      // row = 64 ushort4
    for (int base = start; base < end; base += 64) {
        int cnt = min(64, end - base);
        float p0 = 0.f, p1 = 0.f, p2 = 0.f, p3 = 0.f;
        int s = 0;
        if (lane < cnt) {
            s = col[base + lane];
            float4 av = as4[s];
            float v;
            v = av.x + adv.x; v = v > 0.f ? v : NEG_SLOPE * v; p0 = __expf(v);
            v = av.y + adv.y; v = v > 0.f ? v : NEG_SLOPE * v; p1 = __expf(v);
            v = av.z + adv.z; v = v > 0.f ? v : NEG_SLOPE * v; p2 = __expf(v);
            v = av.w + adv.w; v = v > 0.f ? v : NEG_SLOPE * v; p3 = __expf(v);
            den0 += p0; den1 += p1; den2 += p2; den3 += p3;
        }
        ss[wv][lane] = s;                                  // wave-private LDS
        ((float4*)sp[wv])[lane] = make_float4(p0, p1, p2, p3);
#pragma unroll 4
        for (int j = 0; j < cnt; ++j) {
            int sj = ss[wv][j];                            // broadcast read
            float4 pj = ((const float4*)sp[wv])[j];        // broadcast read
            ushort4 xv = xw24[(size_t)sj * 64 + lane];     // 8B/lane coalesced
            acc0 = fmaf(pj.x, bf2f(xv.x), acc0);
            acc1 = fmaf(pj.y, bf2f(xv.y), acc1);
            acc2 = fmaf(pj.z, bf2f(xv.z), acc2);
            acc3 = fmaf(pj.w, bf2f(xv.w), acc3);
        }
    }
#pragma unroll
    for (int mk = 1; mk < 64; mk <<= 1) {
        den0 += __shfl_xor(den0, mk);
        den1 += __shfl_xor(den1, mk);
        den2 += __shfl_xor(den2, mk);
        den3 += __shfl_xor(den3, mk);
    }

    float o0 = acc0 / (den0 + 1e-16f) + b2[lane];
    float o1 = acc1 / (den1 + 1e-16f) + b2[64 + lane];
    float o2 = acc2 / (den2 + 1e-16f) + b2[128 + lane];
    float o3 = acc3 / (den3 + 1e-16f) + b2[192 + lane];
    o0 = o0 > 0.f ? o0 : expm1f(o0);
    o1 = o1 > 0.f ? o1 : expm1f(o1);
    o2 = o2 > 0.f ? o2 : expm1f(o2);
    o3 = o3 > 0.f ? o3 : expm1f(o3);
    const float2* w32 = (const float2*)W3;     // W3[256][2]
    float2 w0 = w32[lane], w1 = w32[64 + lane];
    float2 w2 = w32[128 + lane], w3 = w32[192 + lane];
    float px = o0 * w0.x + o1 * w1.x + o2 * w2.x + o3 * w3.x;
    float py = o0 * w0.y + o1 * w1.y + o2 * w2.y + o3 * w3.y;
#pragma unroll
    for (int mk = 1; mk < 64; mk <<= 1) {
        px += __shfl_xor(px, mk);
        py += __shfl_xor(py, mk);
    }
    if (lane == 0) {
        float di = dinv[d];
        xw3[d] = make_float2(px * di, py * di);
    }
}

// ---------------- GCN2 aggregate: out = dinv[d]*sum_s xw3[s] + b3 -----------
__global__ void k_agg3(const int* __restrict__ rowptr, const int* __restrict__ col,
        const float2* __restrict__ xw3, const float* __restrict__ dinv,
        const float* __restrict__ b3, float* __restrict__ out) {
    int d = blockIdx.x * 256 + threadIdx.x;
    if (d >= N_NODES) return;
    int e = rowptr[d], end = rowptr[d + 1];
    float a0 = 0.f, a1 = 0.f;
    for (; e < end; ++e) {
        float2 v = xw3[col[e]];
        a0 += v.x; a1 += v.y;
    }
    float di = dinv[d];
    out[d * 2 + 0] = fmaf(a0, di, b3[0]);
    out[d * 2 + 1] = fmaf(a1, di, b3[1]);
}

// ---------------- launch ----------------

extern "C" void kernel_launch(void* const* d_in, const int* in_sizes, int n_in,
                              void* d_out, int out_size, void* d_ws, size_t ws_size,
                              hipStream_t stream) {
    const float* x       = (const float*)d_in[0];
    const int*   ei      = (const int*)d_in[1];
    const float* W1      = (const float*)d_in[2];
    const float* b1      = (const float*)d_in[3];
    const float* W2      = (const float*)d_in[4];
    const float* att_src = (const float*)d_in[5];
    const float* att_dst = (const float*)d_in[6];
    const float* b2      = (const float*)d_in[7];
    const float* W3      = (const float*)d_in[8];
    const float* b3      = (const float*)d_in[9];
    float* out = (float*)d_out;
    (void)in_sizes; (void)n_in; (void)out_size; (void)ws_size;

    char* ws = (char*)d_ws;
    size_t off = 0;
    auto alloc = [&](size_t bytes) -> void* {
        void* p = ws + off;
        off = (off + bytes + 255) & ~(size_t)255;
        return p;
    };
    int*    rowptr = (int*)alloc((N_NODES + 1) * sizeof(int));
    int*    cnt    = (int*)alloc(N_NODES * sizeof(int));
    int*    bsum   = (int*)alloc(NSB * sizeof(int));
    int*    rank   = (int*)alloc((size_t)N_EDGES * sizeof(int));
    int*    col    = (int*)alloc((size_t)E2 * sizeof(int));
    float*  dinv   = (float*)alloc(N_NODES * sizeof(float));
    unsigned short* W2t  = (unsigned short*)alloc(64 * 256 * sizeof(unsigned short));
    unsigned short* wsdt = (unsigned short*)alloc(16 * 64 * sizeof(unsigned short));
    unsigned short* xw1b = (unsigned short*)alloc((size_t)N_NODES * HID * sizeof(unsigned short));
    unsigned short* h1b  = (unsigned short*)alloc((size_t)N_NODES * HID * sizeof(unsigned short));
    float*  a_s    = (float*)alloc((size_t)N_NODES * HEADS * sizeof(float));
    float*  a_d    = (float*)alloc((size_t)N_NODES * HEADS * sizeof(float));
    unsigned short* xw2b = (unsigned short*)alloc((size_t)N_NODES * HH * sizeof(unsigned short));
    float2* xw3    = (float2*)alloc((size_t)N_NODES * sizeof(float2));

    hipMemsetAsync(cnt, 0, N_NODES * sizeof(int), stream);
    k_prep<<<66, 256, 0, stream>>>(W2, att_src, att_dst, W2t, wsdt);
    k_hist<<<NCHUNK, 256, 0, stream>>>(ei + N_EDGES, cnt, rank);
    k_scan1<<<NSB, 256, 0, stream>>>(cnt, bsum);
    k_scan3<<<NSB, 256, 0, stream>>>(cnt, bsum, rowptr, dinv, col);
    k_fill<<<NCHUNK * NRANGE, 256, 0, stream>>>(ei, rowptr, rank, col);

    k_gemm1<<<N_NODES / 32, 256, 0, stream>>>(x, W1, dinv, xw1b);
    k_agg1<<<(N_NODES + 3) / 4, 256, 0, stream>>>(rowptr, col, xw1b, dinv, b1, h1b);
    k_gemm2m<<<(N_NODES / 16) / RT, 256, 0, stream>>>(h1b, W2t, wsdt, xw2b, a_s, a_d);
    const int HALF = 50000;                       // nodes per half
    k_agg2<<<HALF / 4, 256, 0, stream>>>(rowptr, col, xw2b, a_s, a_d, b2, W3, dinv, xw3, 0);
    k_agg2<<<(N_NODES - HALF + 3) / 4, 256, 0, stream>>>(rowptr, col, xw2b, a_s, a_d, b2, W3, dinv, xw3, HALF);
    k_agg3<<<(N_NODES + 255) / 256, 256, 0, stream>>>(rowptr, col, xw3, dinv, b3, out);
}

// Round 12
// 463.626 us; speedup vs baseline: 1.3983x; 1.0557x over previous
//
#include <hip/hip_runtime.h>
#include <math.h>

// Problem constants (from reference)
#define N_NODES 100000
#define N_EDGES 1600000
#define E2      (N_NODES + N_EDGES)   // edges incl. self-loops = 1,700,000
#define IN_C    128
#define HID     64
#define HEADS   4
#define HH      256                    // HEADS*HID
#define OUT_C   2
#define NEG_SLOPE 0.2f

#define SB   1024                      // elements per scan block
#define NSB  ((N_NODES + SB - 1) / SB) // 98
#define NCHUNK 6250                    // fill chunks (6250*256 == N_EDGES)
#define NRANGE 8                       // dst ranges (bands of 12500 nodes)
#define RDIV   12500
#define RT     10                      // row-tiles (16 rows) per gemm2m block
#define NT1    6250                    // gemm1m row-tiles (16 rows each)

typedef __attribute__((ext_vector_type(8))) short bf16x8;
typedef __attribute__((ext_vector_type(4))) float f32x4;

__device__ __forceinline__ float bf2f(unsigned short u) {
    return __uint_as_float(((unsigned)u) << 16);
}
__device__ __forceinline__ unsigned short f2bf(float f) {
    unsigned u = __float_as_uint(f);
    u += 0x7fffu + ((u >> 16) & 1u);   // RNE
    return (unsigned short)(u >> 16);
}

// ---------------- CSR build ----------------
// cnt[] counts REAL edges only; degree = cnt+1 (self-loop at slot 0, placed
// by k_scan3). hist emits rank[i] so fill needs NO atomics. Fill is
// range-banded: blocks writing one dst band are contiguous in dispatch order
// so col writes cluster and merge in cache (round 10 fixed 64B/edge wb).

__global__ void k_hist(const int* __restrict__ dst, int* __restrict__ cnt,
                       int* __restrict__ rank) {
    int i = blockIdx.x * 256 + threadIdx.x;
    if (i >= N_EDGES) return;
    rank[i] = atomicAdd(&cnt[dst[i]], 1);
}

// prep (runs first): b<64: W2t transpose; b in [64,66): wsdt; b in [66,98):
// W1t transpose; b in [98,196): zero cnt (replaces hipMemsetAsync dispatch).
__global__ __launch_bounds__(256) void k_prep(const float* __restrict__ W2,
        const float* __restrict__ W1,
        const float* __restrict__ att_src, const float* __restrict__ att_dst,
        unsigned short* __restrict__ W2t, unsigned short* __restrict__ wsdt,
        unsigned short* __restrict__ W1t, int* __restrict__ cnt) {
    int b = blockIdx.x, t = threadIdx.x;
    if (b < 64) {                       // W2t[n*64+k] = bf16(W2[k][n])
        int g = b * 256 + t;            // g = k*256 + n
        int k = g >> 8, n = g & 255;
        W2t[n * 64 + k] = f2bf(W2[g]);
        return;
    }
    if (b < 66) {                       // wsdt[o*64+k], cols 8..15 zeroed
        int g = (b - 64) * 256 + t;     // 0..511
        wsdt[512 + g] = 0;
        int k = g >> 3, o = g & 7;
        int h = o & 3;
        const float* att = (o < 4) ? att_src : att_dst;
        float acc = 0.f;
        const float* wrow = W2 + (size_t)k * HH + h * 64;
        const float* arow = att + h * 64;
        for (int c = 0; c < 64; ++c) acc = fmaf(wrow[c], arow[c], acc);
        wsdt[o * 64 + k] = f2bf(acc);
        return;
    }
    if (b < 98) {                       // W1t[n*128+k] = bf16(W1[k][n])
        int g = (b - 66) * 256 + t;     // 0..8191, g = k*64 + n
        int k = g >> 6, n = g & 63;
        W1t[n * 128 + k] = f2bf(W1[g]);
        return;
    }
    int i = ((b - 98) * 256 + t) * 4;   // zero cnt
    if (i + 3 < N_NODES) *(int4*)(cnt + i) = make_int4(0, 0, 0, 0);
    else for (int k = 0; k < 4; ++k) if (i + k < N_NODES) cnt[i + k] = 0;
}

// scan1: per-block sums of (cnt+1) -> bsum[NSB]
__global__ __launch_bounds__(256) void k_scan1(const int* __restrict__ cnt,
                                               int* __restrict__ bsum) {
    int b = blockIdx.x, t = threadIdx.x;
    int i = b * SB + t * 4;
    int s = 0;
    if (i + 3 < N_NODES) {
        int4 v = *(const int4*)(cnt + i);
        s = (v.x + v.y) + (v.z + v.w) + 4;       // +1 self-loop per node
    } else {
        for (int k = 0; k < 4; ++k) if (i + k < N_NODES) s += cnt[i + k] + 1;
    }
#pragma unroll
    for (int off = 1; off < 64; off <<= 1) s += __shfl_xor(s, off);
    __shared__ int wsum[4];
    int lane = t & 63, wv = t >> 6;
    if (lane == 0) wsum[wv] = s;
    __syncthreads();
    if (t == 0) bsum[b] = (wsum[0] + wsum[1]) + (wsum[2] + wsum[3]);
}

// scan3: block b computes prefix over bsum[0..b) itself, scans its chunk
// (deg = cnt+1), writes rowptr + dinv, pre-places self-loops at slot 0.
__global__ __launch_bounds__(256) void k_scan3(const int* __restrict__ cnt,
        const int* __restrict__ bsum, int* __restrict__ rowptr,
        float* __restrict__ dinv, int* __restrict__ col) {
    int b = blockIdx.x, t = threadIdx.x;
    int lane = t & 63, wv = t >> 6;
    __shared__ int wred[4];
    {
        int v = (t < b) ? bsum[t] : 0;   // b <= 98 <= 256
#pragma unroll
        for (int off = 1; off < 64; off <<= 1) v += __shfl_xor(v, off);
        if (lane == 0) wred[wv] = v;
    }
    __syncthreads();
    int pre = (wred[0] + wred[1]) + (wred[2] + wred[3]);
    __syncthreads();

    int i = b * SB + t * 4;
    int c0 = 0, c1 = 0, c2 = 0, c3 = 0;
    if (i + 3 < N_NODES) {
        int4 v = *(const int4*)(cnt + i);
        c0 = v.x; c1 = v.y; c2 = v.z; c3 = v.w;
    } else if (i < N_NODES) {
        c0 = cnt[i];
        if (i + 1 < N_NODES) c1 = cnt[i + 1];
        if (i + 2 < N_NODES) c2 = cnt[i + 2];
    }
    int n0 = (i < N_NODES), n1 = (i + 1 < N_NODES),
        n2 = (i + 2 < N_NODES), n3 = (i + 3 < N_NODES);
    int d0 = c0 + n0, d1 = c1 + n1, d2 = c2 + n2, d3 = c3 + n3;  // degrees
    int s = (d0 + d1) + (d2 + d3);
    int inc = s;
#pragma unroll
    for (int off = 1; off < 64; off <<= 1) {
        int u = __shfl_up(inc, off);
        if (lane >= off) inc += u;
    }
    __shared__ int wtot[4];
    if (lane == 63) wtot[wv] = inc;
    __syncthreads();
    int base = pre + (inc - s);
    for (int w = 0; w < wv; ++w) base += wtot[w];
    if (n0) { rowptr[i]     = base;                dinv[i]     = rsqrtf((float)d0); col[base] = i; }
    if (n1) { rowptr[i + 1] = base + d0;           dinv[i + 1] = rsqrtf((float)d1); col[base + d0] = i + 1; }
    if (n2) { rowptr[i + 2] = base + d0 + d1;      dinv[i + 2] = rsqrtf((float)d2); col[base + d0 + d1] = i + 2; }
    if (n3) { rowptr[i + 3] = base + d0 + d1 + d2; dinv[i + 3] = rsqrtf((float)d3); col[base + d0 + d1 + d2] = i + 3; }
    if (b == 0 && t == 0) rowptr[N_NODES] = E2;
}

// fill: atomic-free banded scatter.
__global__ void k_fill(const int* __restrict__ ei, const int* __restrict__ rowptr,
                       const int* __restrict__ rank, int* __restrict__ col) {
    int r = blockIdx.x / NCHUNK;
    int c = blockIdx.x - r * NCHUNK;
    int i = c * 256 + threadIdx.x;          // NCHUNK*256 == N_EDGES exactly
    int d = ei[N_EDGES + i];
    if (d / RDIV != r) return;
    col[rowptr[d] + 1 + rank[i]] = ei[i];   // slot 0 = self-loop
}

// ---------------- GEMM1 via MFMA: xw1b = bf16((x @ W1) * dinv) --------------
// Wave per 16-row tile; B = W1t (W1^T bf16) persistent in VGPRs (16 frags);
// A converted fp32->bf16 in-flight. Same verified fragment pattern as gemm2m.
__global__ __launch_bounds__(256) void k_gemm1m(const float* __restrict__ x,
        const unsigned short* __restrict__ W1t, const float* __restrict__ dinv,
        unsigned short* __restrict__ xw1b) {
    int t = threadIdx.x;
    int lane = t & 63, wv = t >> 6;
    int m = lane & 15, quad = lane >> 4;
    bf16x8 B[4][4];
#pragma unroll
    for (int ct = 0; ct < 4; ++ct)
#pragma unroll
        for (int ks = 0; ks < 4; ++ks)
            B[ct][ks] = *(const bf16x8*)(W1t + (size_t)(ct * 16 + m) * IN_C
                                         + ks * 32 + quad * 8);
    int tile = blockIdx.x * 4 + wv;
    if (tile >= NT1) return;
    int rbase = tile * 16;
    const float* xp = x + (size_t)(rbase + m) * IN_C + quad * 8;
    f32x4 c0 = {0.f, 0.f, 0.f, 0.f}, c1 = c0, c2 = c0, c3 = c0;
#pragma unroll
    for (int ks = 0; ks < 4; ++ks) {
        float4 f0 = *(const float4*)(xp + ks * 32);
        float4 f1 = *(const float4*)(xp + ks * 32 + 4);
        bf16x8 a;
        a[0] = (short)f2bf(f0.x); a[1] = (short)f2bf(f0.y);
        a[2] = (short)f2bf(f0.z); a[3] = (short)f2bf(f0.w);
        a[4] = (short)f2bf(f1.x); a[5] = (short)f2bf(f1.y);
        a[6] = (short)f2bf(f1.z); a[7] = (short)f2bf(f1.w);
        c0 = __builtin_amdgcn_mfma_f32_16x16x32_bf16(a, B[0][ks], c0, 0, 0, 0);
        c1 = __builtin_amdgcn_mfma_f32_16x16x32_bf16(a, B[1][ks], c1, 0, 0, 0);
        c2 = __builtin_amdgcn_mfma_f32_16x16x32_bf16(a, B[2][ks], c2, 0, 0, 0);
        c3 = __builtin_amdgcn_mfma_f32_16x16x32_bf16(a, B[3][ks], c3, 0, 0, 0);
    }
    // C/D: col = ct*16 + m, row = rbase + quad*4 + r
    int row0 = rbase + quad * 4;
    float dv[4];
#pragma unroll
    for (int r = 0; r < 4; ++r) dv[r] = dinv[row0 + r];
#pragma unroll
    for (int ct = 0; ct < 4; ++ct) {
        f32x4 c = (ct == 0) ? c0 : (ct == 1) ? c1 : (ct == 2) ? c2 : c3;
        unsigned short* p = xw1b + (size_t)row0 * HID + ct * 16 + m;
#pragma unroll
        for (int r = 0; r < 4; ++r) p[(size_t)r * HID] = f2bf(c[r] * dv[r]);
    }
}

// ---------------- GCN1 aggregate: h1b = bf16(relu(dinv*sum + b1)) -----------
__global__ __launch_bounds__(256) void k_agg1(const int* __restrict__ rowptr,
        const int* __restrict__ col, const unsigned short* __restrict__ xw1b,
        const float* __restrict__ dinv, const float* __restrict__ b1,
        unsigned short* __restrict__ h1b) {
    int t = threadIdx.x;
    int lane = t & 63;
    int d = blockIdx.x * 4 + (t >> 6);
    if (d >= N_NODES) return;
    int start = rowptr[d], end = rowptr[d + 1];
    int sub = lane >> 4;       // which of 4 edges in a group
    int cpos = lane & 15;      // channel quad (4 bf16)
    float4 acc = make_float4(0.f, 0.f, 0.f, 0.f);
    for (int base = start; base < end; base += 64) {
        int cnt = min(64, end - base);
        int sl = (base + lane < end) ? col[base + lane] : 0;
#pragma unroll 2
        for (int j = 0; j < cnt; j += 4) {
            int idx = j + sub;
            int sj = __shfl(sl, idx);
            if (idx < cnt) {
                ushort4 v = ((const ushort4*)(xw1b + (size_t)sj * HID))[cpos];
                acc.x += bf2f(v.x); acc.y += bf2f(v.y);
                acc.z += bf2f(v.z); acc.w += bf2f(v.w);
            }
        }
    }
    acc.x += __shfl_xor(acc.x, 16); acc.y += __shfl_xor(acc.y, 16);
    acc.z += __shfl_xor(acc.z, 16); acc.w += __shfl_xor(acc.w, 16);
    acc.x += __shfl_xor(acc.x, 32); acc.y += __shfl_xor(acc.y, 32);
    acc.z += __shfl_xor(acc.z, 32); acc.w += __shfl_xor(acc.w, 32);
    if (lane < 16) {
        float di = dinv[d];
        float4 b = ((const float4*)b1)[lane];
        float ox = fmaf(acc.x, di, b.x); ox = ox > 0.f ? ox : 0.f;
        float oy = fmaf(acc.y, di, b.y); oy = oy > 0.f ? oy : 0.f;
        float oz = fmaf(acc.z, di, b.z); oz = oz > 0.f ? oz : 0.f;
        float ow = fmaf(acc.w, di, b.w); ow = ow > 0.f ? ow : 0.f;
        ushort4 o = make_ushort4(f2bf(ox), f2bf(oy), f2bf(oz), f2bf(ow));
        ((ushort4*)(h1b + (size_t)d * HID))[lane] = o;
    }
}

// ---------------- GEMM2 via MFMA: xw2b, a_s, a_d ----------------------------
__global__ __launch_bounds__(256) void k_gemm2m(
        const unsigned short* __restrict__ h1b,
        const unsigned short* __restrict__ W2t,
        const unsigned short* __restrict__ wsdt,
        unsigned short* __restrict__ xw2b,
        float* __restrict__ a_s, float* __restrict__ a_d) {
    int t = threadIdx.x;
    int lane = t & 63, wv = t >> 6;
    int m = lane & 15, quad = lane >> 4;
    int nb = wv * 64 + m;            // this lane's base output column
    bf16x8 B[4][2];
#pragma unroll
    for (int ct = 0; ct < 4; ++ct)
#pragma unroll
        for (int ks = 0; ks < 2; ++ks)
            B[ct][ks] = *(const bf16x8*)(W2t + (size_t)(nb + ct * 16) * 64
                                         + ks * 32 + quad * 8);
    bf16x8 Bw0 = *(const bf16x8*)(wsdt + (size_t)m * 64 + quad * 8);
    bf16x8 Bw1 = *(const bf16x8*)(wsdt + (size_t)m * 64 + 32 + quad * 8);

    int r0 = blockIdx.x * (RT * 16);
    for (int tile = 0; tile < RT; ++tile) {
        int rbase = r0 + tile * 16;
        const unsigned short* ap = h1b + (size_t)(rbase + m) * 64 + quad * 8;
        bf16x8 a0 = *(const bf16x8*)(ap);
        bf16x8 a1 = *(const bf16x8*)(ap + 32);
        f32x4 c0 = {0.f, 0.f, 0.f, 0.f}, c1 = c0, c2 = c0, c3 = c0;
        c0 = __builtin_amdgcn_mfma_f32_16x16x32_bf16(a0, B[0][0], c0, 0, 0, 0);
        c1 = __builtin_amdgcn_mfma_f32_16x16x32_bf16(a0, B[1][0], c1, 0, 0, 0);
        c2 = __builtin_amdgcn_mfma_f32_16x16x32_bf16(a0, B[2][0], c2, 0, 0, 0);
        c3 = __builtin_amdgcn_mfma_f32_16x16x32_bf16(a0, B[3][0], c3, 0, 0, 0);
        c0 = __builtin_amdgcn_mfma_f32_16x16x32_bf16(a1, B[0][1], c0, 0, 0, 0);
        c1 = __builtin_amdgcn_mfma_f32_16x16x32_bf16(a1, B[1][1], c1, 0, 0, 0);
        c2 = __builtin_amdgcn_mfma_f32_16x16x32_bf16(a1, B[2][1], c2, 0, 0, 0);
        c3 = __builtin_amdgcn_mfma_f32_16x16x32_bf16(a1, B[3][1], c3, 0, 0, 0);
        int row = rbase + quad * 4;
        // interleaved layout xw2b[r][c*4+h] with n = h*64+c
#pragma unroll
        for (int ct = 0; ct < 4; ++ct) {
            int n = nb + ct * 16;
            unsigned short* p = xw2b + (size_t)row * HH + (n & 63) * 4 + (n >> 6);
            f32x4 c = (ct == 0) ? c0 : (ct == 1) ? c1 : (ct == 2) ? c2 : c3;
            p[0]       = f2bf(c[0]);
            p[HH]      = f2bf(c[1]);
            p[2 * HH]  = f2bf(c[2]);
            p[3 * HH]  = f2bf(c[3]);
        }
        if (wv == 0) {
            f32x4 aw = {0.f, 0.f, 0.f, 0.f};
            aw = __builtin_amdgcn_mfma_f32_16x16x32_bf16(a0, Bw0, aw, 0, 0, 0);
            aw = __builtin_amdgcn_mfma_f32_16x16x32_bf16(a1, Bw1, aw, 0, 0, 0);
            if (m < 4) {
#pragma unroll
                for (int r = 0; r < 4; ++r) a_s[(row + r) * 4 + m] = aw[r];
            } else if (m < 8) {
#pragma unroll
                for (int r = 0; r < 4; ++r) a_d[(row + r) * 4 + (m - 4)] = aw[r];
            }
        }
    }
}

// ---------------- GAT aggregate + ELU + fused GEMM3 -------------------------
// unroll 4: unroll 8 raised VGPR 32->48, occupancy 79->48%, dur +14% (round 5)
// TWO half-range dispatches: keeps sub-max kernels visible in the top-5
// profile window (the window only ever shows the global max dispatch).
__global__ __launch_bounds__(256) void k_agg2(const int* __restrict__ rowptr,
        const int* __restrict__ col, const unsigned short* __restrict__ xw2b,
        const float* __restrict__ a_s, const float* __restrict__ a_d,
        const float* __restrict__ b2, const float* __restrict__ W3,
        const float* __restrict__ dinv, float2* __restrict__ xw3, int dbase) {
    __shared__ int   ss[4][64];      // 1 KB
    __shared__ float sp[4][64][4];   // 4 KB
    int t = threadIdx.x;
    int lane = t & 63, wv = t >> 6;
    int d = dbase + blockIdx.x * 4 + wv;
    if (d >= N_NODES) return;
    const float4* as4 = (const float4*)a_s;
    float4 adv = ((const float4*)a_d)[d];
    int start = rowptr[d], end = rowptr[d + 1];

    float den0 = 0.f, den1 = 0.f, den2 = 0.f, den3 = 0.f;
    float acc0 = 0.f, acc1 = 0.f, acc2 = 0.f, acc3 = 0.f;
    const ushort4* xw24 = (const ushort4*)xw2b;      // row = 64 ushort4
    for (int base = start; base < end; base += 64) {
        int cnt = min(64, end - base);
        float p0 = 0.f, p1 = 0.f, p2 = 0.f, p3 = 0.f;
        int s = 0;
        if (lane < cnt) {
            s = col[base + lane];
            float4 av = as4[s];
            float v;
            v = av.x + adv.x; v = v > 0.f ? v : NEG_SLOPE * v; p0 = __expf(v);
            v = av.y + adv.y; v = v > 0.f ? v : NEG_SLOPE * v; p1 = __expf(v);
            v = av.z + adv.z; v = v > 0.f ? v : NEG_SLOPE * v; p2 = __expf(v);
            v = av.w + adv.w; v = v > 0.f ? v : NEG_SLOPE * v; p3 = __expf(v);
            den0 += p0; den1 += p1; den2 += p2; den3 += p3;
        }
        ss[wv][lane] = s;                                  // wave-private LDS
        ((float4*)sp[wv])[lane] = make_float4(p0, p1, p2, p3);
#pragma unroll 4
        for (int j = 0; j < cnt; ++j) {
            int sj = ss[wv][j];                            // broadcast read
            float4 pj = ((const float4*)sp[wv])[j];        // broadcast read
            ushort4 xv = xw24[(size_t)sj * 64 + lane];     // 8B/lane coalesced
            acc0 = fmaf(pj.x, bf2f(xv.x), acc0);
            acc1 = fmaf(pj.y, bf2f(xv.y), acc1);
            acc2 = fmaf(pj.z, bf2f(xv.z), acc2);
            acc3 = fmaf(pj.w, bf2f(xv.w), acc3);
        }
    }
#pragma unroll
    for (int mk = 1; mk < 64; mk <<= 1) {
        den0 += __shfl_xor(den0, mk);
        den1 += __shfl_xor(den1, mk);
        den2 += __shfl_xor(den2, mk);
        den3 += __shfl_xor(den3, mk);
    }

    float o0 = acc0 / (den0 + 1e-16f) + b2[lane];
    float o1 = acc1 / (den1 + 1e-16f) + b2[64 + lane];
    float o2 = acc2 / (den2 + 1e-16f) + b2[128 + lane];
    float o3 = acc3 / (den3 + 1e-16f) + b2[192 + lane];
    o0 = o0 > 0.f ? o0 : expm1f(o0);
    o1 = o1 > 0.f ? o1 : expm1f(o1);
    o2 = o2 > 0.f ? o2 : expm1f(o2);
    o3 = o3 > 0.f ? o3 : expm1f(o3);
    const float2* w32 = (const float2*)W3;     // W3[256][2]
    float2 w0 = w32[lane], w1 = w32[64 + lane];
    float2 w2 = w32[128 + lane], w3 = w32[192 + lane];
    float px = o0 * w0.x + o1 * w1.x + o2 * w2.x + o3 * w3.x;
    float py = o0 * w0.y + o1 * w1.y + o2 * w2.y + o3 * w3.y;
#pragma unroll
    for (int mk = 1; mk < 64; mk <<= 1) {
        px += __shfl_xor(px, mk);
        py += __shfl_xor(py, mk);
    }
    if (lane == 0) {
        float di = dinv[d];
        xw3[d] = make_float2(px * di, py * di);
    }
}

// ---------------- GCN2 aggregate: out = dinv[d]*sum_s xw3[s] + b3 -----------
__global__ void k_agg3(const int* __restrict__ rowptr, const int* __restrict__ col,
        const float2* __restrict__ xw3, const float* __restrict__ dinv,
        const float* __restrict__ b3, float* __restrict__ out) {
    int d = blockIdx.x * 256 + threadIdx.x;
    if (d >= N_NODES) return;
    int e = rowptr[d], end = rowptr[d + 1];
    float a0 = 0.f, a1 = 0.f;
    for (; e < end; ++e) {
        float2 v = xw3[col[e]];
        a0 += v.x; a1 += v.y;
    }
    float di = dinv[d];
    out[d * 2 + 0] = fmaf(a0, di, b3[0]);
    out[d * 2 + 1] = fmaf(a1, di, b3[1]);
}

// ---------------- launch ----------------

extern "C" void kernel_launch(void* const* d_in, const int* in_sizes, int n_in,
                              void* d_out, int out_size, void* d_ws, size_t ws_size,
                              hipStream_t stream) {
    const float* x       = (const float*)d_in[0];
    const int*   ei      = (const int*)d_in[1];
    const float* W1      = (const float*)d_in[2];
    const float* b1      = (const float*)d_in[3];
    const float* W2      = (const float*)d_in[4];
    const float* att_src = (const float*)d_in[5];
    const float* att_dst = (const float*)d_in[6];
    const float* b2      = (const float*)d_in[7];
    const float* W3      = (const float*)d_in[8];
    const float* b3      = (const float*)d_in[9];
    float* out = (float*)d_out;
    (void)in_sizes; (void)n_in; (void)out_size; (void)ws_size;

    char* ws = (char*)d_ws;
    size_t off = 0;
    auto alloc = [&](size_t bytes) -> void* {
        void* p = ws + off;
        off = (off + bytes + 255) & ~(size_t)255;
        return p;
    };
    int*    rowptr = (int*)alloc((N_NODES + 1) * sizeof(int));
    int*    cnt    = (int*)alloc(N_NODES * sizeof(int));
    int*    bsum   = (int*)alloc(NSB * sizeof(int));
    int*    rank   = (int*)alloc((size_t)N_EDGES * sizeof(int));
    int*    col    = (int*)alloc((size_t)E2 * sizeof(int));
    float*  dinv   = (float*)alloc(N_NODES * sizeof(float));
    unsigned short* W2t  = (unsigned short*)alloc(64 * 256 * sizeof(unsigned short));
    unsigned short* wsdt = (unsigned short*)alloc(16 * 64 * sizeof(unsigned short));
    unsigned short* W1t  = (unsigned short*)alloc(64 * 128 * sizeof(unsigned short));
    unsigned short* xw1b = (unsigned short*)alloc((size_t)N_NODES * HID * sizeof(unsigned short));
    unsigned short* h1b  = (unsigned short*)alloc((size_t)N_NODES * HID * sizeof(unsigned short));
    float*  a_s    = (float*)alloc((size_t)N_NODES * HEADS * sizeof(float));
    float*  a_d    = (float*)alloc((size_t)N_NODES * HEADS * sizeof(float));
    unsigned short* xw2b = (unsigned short*)alloc((size_t)N_NODES * HH * sizeof(unsigned short));
    float2* xw3    = (float2*)alloc((size_t)N_NODES * sizeof(float2));

    k_prep<<<196, 256, 0, stream>>>(W2, W1, att_src, att_dst, W2t, wsdt, W1t, cnt);
    k_hist<<<NCHUNK, 256, 0, stream>>>(ei + N_EDGES, cnt, rank);
    k_scan1<<<NSB, 256, 0, stream>>>(cnt, bsum);
    k_scan3<<<NSB, 256, 0, stream>>>(cnt, bsum, rowptr, dinv, col);
    k_fill<<<NCHUNK * NRANGE, 256, 0, stream>>>(ei, rowptr, rank, col);

    k_gemm1m<<<(NT1 + 3) / 4, 256, 0, stream>>>(x, W1t, dinv, xw1b);
    k_agg1<<<(N_NODES + 3) / 4, 256, 0, stream>>>(rowptr, col, xw1b, dinv, b1, h1b);
    k_gemm2m<<<(N_NODES / 16) / RT, 256, 0, stream>>>(h1b, W2t, wsdt, xw2b, a_s, a_d);
    const int HALF = 50000;                       // nodes per half
    k_agg2<<<HALF / 4, 256, 0, stream>>>(rowptr, col, xw2b, a_s, a_d, b2, W3, dinv, xw3, 0);
    k_agg2<<<(N_NODES - HALF + 3) / 4, 256, 0, stream>>>(rowptr, col, xw2b, a_s, a_d, b2, W3, dinv, xw3, HALF);
    k_agg3<<<(N_NODES + 255) / 256, 256, 0, stream>>>(rowptr, col, xw3, dinv, b3, out);
}